// Round 3
// baseline (140.277 us; speedup 1.0000x reference)
//
#include <hip/hip_runtime.h>
#include <math.h>

#define B_DIM 16
#define C_DIM 256
#define NV    40962
#define K_NEI 7
#define NPAIR (NV / 2)   // 20481

typedef float v2f __attribute__((ext_vector_type(2)));

// Kernel 1 (fused pool + transpose): channel-wise mean+max reduction over
// x[b][c][n], writing DIRECTLY in transposed layout poolT[n][b] (float2(avg,max)).
// Reads: thread owns 2 consecutive n for one b -> wave reads contiguous 512B,
// non-temporal (x streamed exactly once; keep L2/L3 clean for poolT/idx).
// Writes: two 8B scatter stores per thread (128B stride in-wave). All 1280
// blocks are co-resident (5 blocks/CU), so each poolT line's 16 byte-disjoint
// writers merge in the L2 window; total volume only 5.2 MB.
__global__ void pool_kernel(const float* __restrict__ x, float2* __restrict__ poolT) {
    int t = blockIdx.x * blockDim.x + threadIdx.x;
    if (t >= B_DIM * NPAIR) return;
    int b  = t / NPAIR;
    int n2 = t - b * NPAIR;

    const float* xb = x + (size_t)b * C_DIM * NV + 2 * (size_t)n2;

    float sx = 0.f, sy = 0.f;
    float mx = -INFINITY, my = -INFINITY;
    #pragma unroll 16
    for (int c = 0; c < C_DIM; ++c) {
        v2f v = __builtin_nontemporal_load(
                    reinterpret_cast<const v2f*>(xb + (size_t)c * NV));
        sx += v.x; sy += v.y;
        mx = fmaxf(mx, v.x);
        my = fmaxf(my, v.y);
    }
    const float inv = 1.0f / (float)C_DIM;

    size_t n = 2 * (size_t)n2;
    poolT[n * 16 + b]       = make_float2(sx * inv, mx);
    poolT[(n + 1) * 16 + b] = make_float2(sy * inv, my);
}

// Kernel 2: one thread per vertex n, all 16 b. Each of the 7 gathers is a
// full 128B line (8x float4, 100% line utilization); idx read once per n;
// stores wave-coalesced per b. Arithmetic order identical to passing version.
__global__ void att2_kernel(const float2* __restrict__ poolT,
                            const int* __restrict__ idx,
                            const float* __restrict__ W,
                            const float* __restrict__ bias,
                            float* __restrict__ out) {
    int n = blockIdx.x * 64 + threadIdx.x;
    if (n >= NV) return;

    float w[2 * K_NEI];
    #pragma unroll
    for (int i = 0; i < 2 * K_NEI; ++i) w[i] = W[i];
    float bb = bias[0];

    float acc[16];
    #pragma unroll
    for (int b = 0; b < 16; ++b) acc[b] = bb;

    #pragma unroll
    for (int k = 0; k < K_NEI; ++k) {
        int j = idx[n * K_NEI + k];
        const float4* L = reinterpret_cast<const float4*>(poolT + (size_t)j * 16);
        #pragma unroll
        for (int q = 0; q < 8; ++q) {
            float4 v = L[q];
            acc[2 * q]     = fmaf(w[2 * k + 1], v.y, fmaf(w[2 * k], v.x, acc[2 * q]));
            acc[2 * q + 1] = fmaf(w[2 * k + 1], v.w, fmaf(w[2 * k], v.z, acc[2 * q + 1]));
        }
    }
    #pragma unroll
    for (int b = 0; b < 16; ++b)
        out[(size_t)b * NV + n] = 1.0f / (1.0f + expf(-acc[b]));
}

extern "C" void kernel_launch(void* const* d_in, const int* in_sizes, int n_in,
                              void* d_out, int out_size, void* d_ws, size_t ws_size,
                              hipStream_t stream) {
    const float* x     = (const float*)d_in[0];
    const int*   neigh = (const int*)  d_in[1];
    const float* W     = (const float*)d_in[2];
    const float* bias  = (const float*)d_in[3];
    float*       out   = (float*)d_out;

    float2* poolT = (float2*)d_ws;    // [NV][16] float2 = 5.24 MB

    int t1 = B_DIM * NPAIR;
    pool_kernel<<<(t1 + 255) / 256, 256, 0, stream>>>(x, poolT);

    int ntile = (NV + 63) / 64;       // 641
    att2_kernel<<<ntile, 64, 0, stream>>>(poolT, neigh, W, bias, out);
}